// Round 4
// baseline (442.042 us; speedup 1.0000x reference)
//
#include <hip/hip_runtime.h>
#include <hip/hip_bf16.h>
#include <math.h>

// ---------- constants ----------
#define Bsz 4
#define Cin 512
#define Hh 16
#define Ww 16
#define Lsp 256
#define DIM 128
#define DM 1024      // dim*4 + 512
#define DI 2048
#define KK 4
#define NST 16
#define RR 64
#define PW 384       // K*96 projection rows
#define NCH 4
#define CHUNK 64     // Lsp / NCH

// ---------- ws layout (floats) ----------
#define OFF_FEAT    0u
#define SZ_FEAT     (Bsz*Lsp*DM)                 // 1048576
#define OFF_POOLED  (OFF_FEAT + SZ_FEAT)
#define SZ_POOLED   (Bsz*Cin*275)                // 563200
#define OFF_PCONV   (OFF_POOLED + SZ_POOLED)
#define SZ_PCONV    (Bsz*275*DIM)                // 140800
#define OFF_Y0M     (OFF_PCONV + SZ_PCONV)
#define SZ_Y0M      (Bsz*DIM)                    // 512
#define OFF_XZ      (OFF_Y0M + SZ_Y0M)
#define SZ_XZ       (Bsz*Lsp*2*DI)               // 4194304
#define OFF_XCT     (OFF_XZ + SZ_XZ)
#define SZ_XCT      (Bsz*Lsp*DI)                 // 2097152 (currently unused)
#define OFF_XDBL    (OFF_XCT + SZ_XCT)
#define SZ_XDBL     (Bsz*Lsp*PW)                 // 393216  (P matrix f32)
#define OFF_DELTA   (OFF_XDBL + SZ_XDBL)
#define SZ_DELTA    (Bsz*KK*Lsp*DI)              // 8388608 (delta_sp f32, 32MB)
#define OFF_OUTY    (OFF_DELTA + SZ_DELTA)
#define SZ_OUTY     (Bsz*KK*Lsp*DI)              // 8388608 (out_y bf16 16MB + Pa 8MB + Hend 8MB)
#define OFF_YG      (OFF_OUTY + SZ_OUTY)
#define SZ_YG       (Bsz*Lsp*DI)                 // 2097152 (Hstart 8MB)
#define OFF_O1      (OFF_YG + SZ_YG)
#define SZ_O1       (Bsz*Lsp*DM)                 // 1048576 (xcB then o1B, 4MB)
#define OFF_O2      (OFF_O1 + SZ_O1)
#define SZ_O2       (Bsz*Lsp*DIM)                // 131072
#define WS_FLOATS   (OFF_O2 + SZ_O2)

typedef __attribute__((ext_vector_type(8))) short short8;
typedef __attribute__((ext_vector_type(4))) float f32x4;

__device__ __forceinline__ short f2bf(float x) {
  __hip_bfloat16 h = __float2bfloat16(x);
  short s;
  __builtin_memcpy(&s, &h, 2);
  return s;
}
__device__ __forceinline__ float bf2f(short s) {
  unsigned u = ((unsigned)(unsigned short)s) << 16;
  float f;
  __builtin_memcpy(&f, &u, 4);
  return f;
}

// ---------- f32 -> bf16 bulk convert (n multiple of 8) ----------
__global__ __launch_bounds__(256) void f2bf_kernel(const float* __restrict__ in,
    short* __restrict__ out, int n) {
  int i = (blockIdx.x*256 + threadIdx.x)*8;
  if (i >= n) return;
  float4 a = *(const float4*)(in + i);
  float4 b = *(const float4*)(in + i + 4);
  short8 o;
  o[0]=f2bf(a.x); o[1]=f2bf(a.y); o[2]=f2bf(a.z); o[3]=f2bf(a.w);
  o[4]=f2bf(b.x); o[5]=f2bf(b.y); o[6]=f2bf(b.z); o[7]=f2bf(b.w);
  *(short8*)(out + i) = o;
}

// ---------- pool layer 0: conv1x1+BN+ReLU then global mean ----------
__global__ __launch_bounds__(256) void pool0_kernel(
    const float* __restrict__ x, const float* __restrict__ pw, const float* __restrict__ pb,
    const float* __restrict__ g, const float* __restrict__ bb,
    const float* __restrict__ m, const float* __restrict__ v, float* __restrict__ y0m) {
  int bd = blockIdx.x;             // b*128+d
  int b = bd >> 7, d = bd & 127;
  int l = threadIdx.x;
  const float* xb = x + (b*Cin)*Lsp + l;
  const float* w = pw + d*Cin;     // layer 0
  float s = 0.f;
  #pragma unroll 4
  for (int c = 0; c < Cin; ++c) s += xb[c*Lsp] * w[c];
  s += pb[d];
  float inv = g[d] * rsqrtf(v[d] + 1e-5f);
  s = s*inv + (bb[d] - m[d]*inv);
  s = fmaxf(s, 0.f);
  __shared__ float red[256];
  red[l] = s; __syncthreads();
  for (int off = 128; off > 0; off >>= 1) {
    if (l < off) red[l] += red[l+off];
    __syncthreads();
  }
  if (l == 0) y0m[bd] = red[0] * (1.f/256.f);
}

// ---------- adaptive avg pool of x to 5x5,9x9,13x13 (concatenated 275 positions) ----------
__device__ __forceinline__ void decode_pos(int pos, int& s, int& pp, int& qq, int& layer) {
  if (pos < 25)       { s = 5;  layer = 1; int t = pos;       pp = t/5;  qq = t%5;  }
  else if (pos < 106) { s = 9;  layer = 2; int t = pos - 25;  pp = t/9;  qq = t%9;  }
  else                { s = 13; layer = 3; int t = pos - 106; pp = t/13; qq = t%13; }
}

__global__ void pool_avg_kernel(const float* __restrict__ x, float* __restrict__ pooled) {
  int bc = blockIdx.x;             // b*512+c
  int pos = threadIdx.x;
  if (pos >= 275) return;
  int s, pp, qq, layer;
  decode_pos(pos, s, pp, qq, layer);
  int hs = (pp*Hh)/s, he = ((pp+1)*Hh + s-1)/s;
  int ws = (qq*Ww)/s, we = ((qq+1)*Ww + s-1)/s;
  const float* xb = x + bc*Lsp;
  float acc = 0.f;
  for (int hh = hs; hh < he; ++hh)
    for (int ww2 = ws; ww2 < we; ++ww2)
      acc += xb[hh*Ww + ww2];
  pooled[bc*275 + pos] = acc / (float)((he-hs)*(we-ws));
}

// ---------- conv1x1 + BN + ReLU on pooled features ----------
__global__ void pconv_kernel(const float* __restrict__ pooled, const float* __restrict__ pw,
    const float* __restrict__ pb, const float* __restrict__ g, const float* __restrict__ bb,
    const float* __restrict__ m, const float* __restrict__ v, float* __restrict__ pconv) {
  int bp = blockIdx.x;             // b*275+pos
  int b = bp / 275, pos = bp % 275;
  int d = threadIdx.x;             // 0..127
  int s, pp, qq, layer;
  decode_pos(pos, s, pp, qq, layer);
  const float* pc = pooled + b*Cin*275 + pos;
  const float* w = pw + (layer*DIM + d)*Cin;
  float acc = 0.f;
  #pragma unroll 4
  for (int c = 0; c < Cin; ++c) acc += pc[c*275] * w[c];
  acc += pb[layer*DIM + d];
  int ld = layer*DIM + d;
  float inv = g[ld] * rsqrtf(v[ld] + 1e-5f);
  acc = acc*inv + (bb[ld] - m[ld]*inv);
  pconv[bp*DIM + d] = fmaxf(acc, 0.f);
}

// ---------- assemble feat (B,L,1024) in bf16 ----------
__global__ __launch_bounds__(256) void feat_kernel(const float* __restrict__ x,
    const float* __restrict__ y0m, const float* __restrict__ pconv, short* __restrict__ featB) {
  int bl = blockIdx.x;             // b*256+l
  int b = bl >> 8, l = bl & 255;
  int h = l >> 4, w = l & 15;
  for (int c = threadIdx.x; c < DM; c += 256) {
    float val;
    if (c < Cin) {
      val = x[(b*Cin + c)*Lsp + l];
    } else if (c < Cin + DIM) {
      val = y0m[b*DIM + (c - Cin)];
    } else {
      int i = (c - (Cin+DIM)) >> 7;          // 0,1,2 -> s=5,9,13
      int d = (c - (Cin+DIM)) & 127;
      int s = (i==0) ? 5 : (i==1) ? 9 : 13;
      int off = (i==0) ? 0 : (i==1) ? 25 : 106;
      float scale = (float)s / 16.f;
      float sh = fmaxf((h + 0.5f)*scale - 0.5f, 0.f);
      int h0 = min((int)sh, s-1); float wh = sh - (float)h0; int h1 = min(h0+1, s-1);
      float sw = fmaxf((w + 0.5f)*scale - 0.5f, 0.f);
      int w0 = min((int)sw, s-1); float ww2 = sw - (float)w0; int w1 = min(w0+1, s-1);
      const float* pc = pconv + b*275*DIM;
      float v00 = pc[(off + h0*s + w0)*DIM + d];
      float v01 = pc[(off + h0*s + w1)*DIM + d];
      float v10 = pc[(off + h1*s + w0)*DIM + d];
      float v11 = pc[(off + h1*s + w1)*DIM + d];
      val = (1.f-wh)*((1.f-ww2)*v00 + ww2*v01) + wh*((1.f-ww2)*v10 + ww2*v11);
    }
    featB[bl*DM + c] = f2bf(val);
  }
}

// ---------- bf16 MFMA GEMM: C[M][N] = A[M][K] * B[N][K]^T ----------
// MODE 0: f32 store.  MODE 1: bf16 store.  MODE 2: f32 softplus(acc + bias[col]).
// 128x128 tile, BK=64, 4 waves (2x2), 4x4 16x16x32 frags per wave.
// LDS via global_load_lds (linear dest) with XOR-swizzled global source + swizzled ds_read.
__device__ __forceinline__ void gload_lds16(const short* g, short* l) {
  __builtin_amdgcn_global_load_lds((const __attribute__((address_space(1))) void*)g,
                                   (__attribute__((address_space(3))) void*)l, 16, 0, 0);
}

template<int MODE>
__global__ __launch_bounds__(256) void gemm_bf(const short* __restrict__ Ag,
    const short* __restrict__ Bg, void* __restrict__ Cout, const float* __restrict__ bias,
    int M, int N, int K, int lda, int ldb) {
  __shared__ short Als[128*64];
  __shared__ short Bls[128*64];
  int tid = threadIdx.x;
  int w = tid >> 6, lane = tid & 63;
  int wm = w >> 1, wn = w & 1;
  int row0 = blockIdx.y * 128, col0 = blockIdx.x * 128;
  f32x4 acc[4][4];
  #pragma unroll
  for (int i = 0; i < 4; ++i)
    #pragma unroll
    for (int j = 0; j < 4; ++j)
      acc[i][j] = (f32x4){0.f, 0.f, 0.f, 0.f};

  for (int k0 = 0; k0 < K; k0 += 64) {
    #pragma unroll
    for (int i = 0; i < 4; ++i) {
      int slot = i*256 + w*64 + lane;
      int r = slot >> 3, pc = slot & 7;
      int c = pc ^ (r & 7);                       // logical 16B-chunk for this slot
      gload_lds16(Ag + (size_t)(row0 + r)*lda + k0 + c*8, &Als[(i*256 + w*64)*8]);
      gload_lds16(Bg + (size_t)(col0 + r)*ldb + k0 + c*8, &Bls[(i*256 + w*64)*8]);
    }
    __syncthreads();
    #pragma unroll
    for (int ks = 0; ks < 2; ++ks) {
      short8 af[4], bfr[4];
      int rsel = lane & 15, csel = ks*4 + (lane >> 4);
      #pragma unroll
      for (int mi = 0; mi < 4; ++mi) {
        int row = wm*64 + mi*16 + rsel;
        af[mi] = *(const short8*)&Als[row*64 + ((csel ^ (row & 7)) << 3)];
      }
      #pragma unroll
      for (int ni = 0; ni < 4; ++ni) {
        int row = wn*64 + ni*16 + rsel;
        bfr[ni] = *(const short8*)&Bls[row*64 + ((csel ^ (row & 7)) << 3)];
      }
      #pragma unroll
      for (int mi = 0; mi < 4; ++mi)
        #pragma unroll
        for (int ni = 0; ni < 4; ++ni)
          acc[mi][ni] = __builtin_amdgcn_mfma_f32_16x16x32_bf16(af[mi], bfr[ni], acc[mi][ni], 0, 0, 0);
    }
    __syncthreads();
  }
  // epilogue: D row = (lane>>4)*4 + j, col = lane&15
  #pragma unroll
  for (int mi = 0; mi < 4; ++mi) {
    int rbase = row0 + wm*64 + mi*16 + ((lane >> 4) << 2);
    #pragma unroll
    for (int ni = 0; ni < 4; ++ni) {
      int colg = col0 + wn*64 + ni*16 + (lane & 15);
      #pragma unroll
      for (int j = 0; j < 4; ++j) {
        if (MODE == 1) {
          ((short*)Cout)[(size_t)(rbase + j)*N + colg] = f2bf(acc[mi][ni][j]);
        } else if (MODE == 2) {
          float sv = acc[mi][ni][j] + bias[colg];
          ((float*)Cout)[(size_t)(rbase + j)*N + colg] = (sv > 20.f) ? sv : log1pf(__expf(sv));
        } else {
          ((float*)Cout)[(size_t)(rbase + j)*N + colg] = acc[mi][ni][j];
        }
      }
    }
  }
}

// ---------- depthwise 3x3 conv + bias + silu -> xcB (bf16) ----------
__global__ __launch_bounds__(256) void dwconv_kernel(const float* __restrict__ xz,
    const float* __restrict__ cw, const float* __restrict__ cb, short* __restrict__ xcB) {
  int bl = blockIdx.x;
  int b = bl >> 8, l = bl & 255;
  int h = l >> 4, w = l & 15;
  const float* xzb = xz + (size_t)b*Lsp*(2*DI);
  for (int d = threadIdx.x; d < DI; d += 256) {
    float s = 0.f;
    #pragma unroll
    for (int dh = -1; dh <= 1; ++dh) {
      int hh = h + dh; if (hh < 0 || hh > 15) continue;
      #pragma unroll
      for (int dw = -1; dw <= 1; ++dw) {
        int ww2 = w + dw; if (ww2 < 0 || ww2 > 15) continue;
        s += xzb[(hh*16 + ww2)*(2*DI) + d] * cw[d*9 + (dh+1)*3 + (dw+1)];
      }
    }
    s += cb[d];
    float r = s / (1.f + __expf(-s));   // silu
    xcB[((size_t)b*Lsp + l)*DI + d] = f2bf(r);
  }
}

// scan-direction spatial index map
__device__ __forceinline__ int dir_map(int k, int l) {
  if (k == 0) return l;
  if (k == 1) return ((l & 15) << 4) | (l >> 4);
  if (k == 2) return 255 - l;
  int m = 255 - l; return ((m & 15) << 4) | (m >> 4);
}

// ---------- scan pass 1: per-chunk local scan -> Pa (decay product), Hend ----------
__global__ __launch_bounds__(256) void scan_pass1(const float* __restrict__ delta_sp,
    const short* __restrict__ xcB, const float* __restrict__ P,
    const float* __restrict__ A_logs, float* __restrict__ Pa, float* __restrict__ Hend) {
  int bk = blockIdx.x;             // b*4+k
  int b = bk >> 2, k = bk & 3;
  int tid = threadIdx.x;
  int wv = tid >> 6, lane = tid & 63;
  int dloc = lane >> 2, ng = lane & 3;
  int d = blockIdx.y*64 + wv*16 + dloc;
  int c = blockIdx.z;
  int n0 = ng*4;
  float A[4], h[4] = {0.f,0.f,0.f,0.f}, pa[4] = {1.f,1.f,1.f,1.f};
  #pragma unroll
  for (int j = 0; j < 4; ++j)
    A[j] = -__expf(A_logs[((size_t)k*DI + d)*NST + n0 + j]);
  const float* dsp = delta_sp + (size_t)(k*Bsz + b)*Lsp*DI;
  const short* xc  = xcB + (size_t)b*Lsp*DI;
  for (int l = c*CHUNK; l < (c+1)*CHUNK; ++l) {
    int sp = dir_map(k, l);
    const float* pr = P + (size_t)(b*Lsp + sp)*PW + k*96;
    float dl = dsp[sp*DI + d];
    float ul = bf2f(xc[sp*DI + d]);
    float du = dl * ul;
    #pragma unroll
    for (int j = 0; j < 4; ++j) {
      float e = __expf(dl*A[j]);
      h[j] = h[j]*e + du*pr[RR + n0 + j];
      pa[j] *= e;
    }
  }
  size_t base = ((size_t)(c*16 + bk)*DI + d)*NST + n0;
  #pragma unroll
  for (int j = 0; j < 4; ++j) {
    Pa[base + j] = pa[j];
    Hend[base + j] = h[j];
  }
}

// ---------- combine chunk boundaries: Hstart[c] = H_{c-1} (true running state) ----------
__global__ __launch_bounds__(256) void scan_combine(const float* __restrict__ Pa,
    const float* __restrict__ Hend, float* __restrict__ Hstart) {
  int idx = blockIdx.x*256 + threadIdx.x;    // (bk*DI + d)*16 + n
  const int stride = 16*DI*NST;              // 524288
  float h = 0.f;
  #pragma unroll
  for (int c = 0; c < NCH; ++c) {
    Hstart[c*stride + idx] = h;
    h = Pa[c*stride + idx]*h + Hend[c*stride + idx];
  }
}

// ---------- scan pass 2: rescan with correct Hstart, emit y (bf16) ----------
__global__ __launch_bounds__(256) void scan_pass2(const float* __restrict__ delta_sp,
    const short* __restrict__ xcB, const float* __restrict__ P,
    const float* __restrict__ A_logs, const float* __restrict__ Ds,
    const float* __restrict__ Hstart, short* __restrict__ oyB) {
  int bk = blockIdx.x;             // b*4+k
  int b = bk >> 2, k = bk & 3;
  int tid = threadIdx.x;
  int wv = tid >> 6, lane = tid & 63;
  int dloc = lane >> 2, ng = lane & 3;
  int d = blockIdx.y*64 + wv*16 + dloc;
  int c = blockIdx.z;
  int n0 = ng*4;
  float A[4], h[4];
  #pragma unroll
  for (int j = 0; j < 4; ++j)
    A[j] = -__expf(A_logs[((size_t)k*DI + d)*NST + n0 + j]);
  size_t hbase = ((size_t)(c*16 + bk)*DI + d)*NST + n0;
  #pragma unroll
  for (int j = 0; j < 4; ++j) h[j] = Hstart[hbase + j];
  float Dv = Ds[k*DI + d];
  const float* dsp = delta_sp + (size_t)(k*Bsz + b)*Lsp*DI;
  const short* xc  = xcB + (size_t)b*Lsp*DI;
  short* oy = oyB + (size_t)bk*Lsp*DI;
  for (int l = c*CHUNK; l < (c+1)*CHUNK; ++l) {
    int sp = dir_map(k, l);
    const float* pr = P + (size_t)(b*Lsp + sp)*PW + k*96;
    float dl = dsp[sp*DI + d];
    float ul = bf2f(xc[sp*DI + d]);
    float du = dl * ul;
    float y = 0.f;
    #pragma unroll
    for (int j = 0; j < 4; ++j) {
      h[j] = h[j]*__expf(dl*A[j]) + du*pr[RR + n0 + j];
      y += h[j]*pr[RR + NST + n0 + j];
    }
    y += __shfl_xor(y, 1);
    y += __shfl_xor(y, 2);
    if (ng == 0) oy[(size_t)l*DI + d] = f2bf(y + Dv*ul);
  }
}

// ---------- combine 4 directions + LayerNorm + gate with silu(z) -> bf16 ----------
__global__ __launch_bounds__(256) void combine_ln_kernel(const short* __restrict__ oyB,
    const float* __restrict__ xz, const float* __restrict__ lng, const float* __restrict__ lnb,
    short* __restrict__ ygB) {
  int bl = blockIdx.x;
  int b = bl >> 8, l = bl & 255;
  int h = l >> 4, w = l & 15;
  int lT = (w << 4) | h;
  const short* oy = oyB + (size_t)b*KK*Lsp*DI;
  float vals[8];
  float sum = 0.f, sumsq = 0.f;
  #pragma unroll
  for (int i = 0; i < 8; ++i) {
    int d = threadIdx.x + i*256;
    float yv = bf2f(oy[(size_t)(0*Lsp + l       )*DI + d])
             + bf2f(oy[(size_t)(2*Lsp + (255-l ))*DI + d])
             + bf2f(oy[(size_t)(1*Lsp + lT      )*DI + d])
             + bf2f(oy[(size_t)(3*Lsp + (255-lT))*DI + d]);
    vals[i] = yv; sum += yv; sumsq += yv*yv;
  }
  __shared__ float r1[256], r2[256];
  r1[threadIdx.x] = sum; r2[threadIdx.x] = sumsq; __syncthreads();
  for (int off = 128; off > 0; off >>= 1) {
    if (threadIdx.x < off) { r1[threadIdx.x] += r1[threadIdx.x+off]; r2[threadIdx.x] += r2[threadIdx.x+off]; }
    __syncthreads();
  }
  float mu = r1[0] * (1.f/2048.f);
  float var = r2[0] * (1.f/2048.f) - mu*mu;
  float rstd = rsqrtf(var + 1e-5f);
  const float* zrow = xz + (size_t)bl*(2*DI) + DI;
  #pragma unroll
  for (int i = 0; i < 8; ++i) {
    int d = threadIdx.x + i*256;
    float z = zrow[d];
    float sz = z / (1.f + __expf(-z));
    ygB[(size_t)bl*DI + d] = f2bf(((vals[i]-mu)*rstd*lng[d] + lnb[d]) * sz);
  }
}

// ---------- cbr epilogue: bias + BN + exact GELU, write NCHW ----------
__global__ void cbr_epilogue(const float* __restrict__ o2, const float* __restrict__ cb,
    const float* __restrict__ g, const float* __restrict__ beta, const float* __restrict__ m_,
    const float* __restrict__ v_, float* __restrict__ out) {
  int idx = blockIdx.x*256 + threadIdx.x;   // (b*128+dd)*256 + l
  int l = idx & 255;
  int rest = idx >> 8;
  int dd = rest & 127;
  int b = rest >> 7;
  float s = o2[((size_t)b*Lsp + l)*DIM + dd] + cb[dd];
  float inv = g[dd] * rsqrtf(v_[dd] + 1e-5f);
  s = s*inv + (beta[dd] - m_[dd]*inv);
  out[idx] = s * 0.5f * (1.f + erff(s * 0.70710678118f));
}

extern "C" void kernel_launch(void* const* d_in, const int* in_sizes, int n_in,
                              void* d_out, int out_size, void* d_ws, size_t ws_size,
                              hipStream_t stream) {
  const float* x        = (const float*)d_in[0];
  const float* pool_w   = (const float*)d_in[1];
  const float* pool_b   = (const float*)d_in[2];
  const float* bn_g     = (const float*)d_in[3];
  const float* bn_b     = (const float*)d_in[4];
  const float* bn_m     = (const float*)d_in[5];
  const float* bn_v     = (const float*)d_in[6];
  const float* in_proj_w= (const float*)d_in[7];
  const float* conv_w   = (const float*)d_in[8];
  const float* conv_b   = (const float*)d_in[9];
  const float* x_proj_w = (const float*)d_in[10];
  const float* dt_w     = (const float*)d_in[11];
  const float* dt_b     = (const float*)d_in[12];
  const float* A_logs   = (const float*)d_in[13];
  const float* Ds       = (const float*)d_in[14];
  const float* ln_g     = (const float*)d_in[15];
  const float* ln_b     = (const float*)d_in[16];
  const float* out_proj_w=(const float*)d_in[17];
  const float* cbr_w    = (const float*)d_in[18];
  const float* cbr_b    = (const float*)d_in[19];
  const float* cbr_g    = (const float*)d_in[20];
  const float* cbr_beta = (const float*)d_in[21];
  const float* cbr_m    = (const float*)d_in[22];
  const float* cbr_v    = (const float*)d_in[23];
  float* out = (float*)d_out;

  if (ws_size < (size_t)WS_FLOATS * sizeof(float)) return;  // not enough scratch
  float* ws = (float*)d_ws;
  float* pooled = ws + OFF_POOLED;
  float* pconv  = ws + OFF_PCONV;
  float* y0m    = ws + OFF_Y0M;
  float* xz     = ws + OFF_XZ;
  float* P      = ws + OFF_XDBL;
  float* delta_sp = ws + OFF_DELTA;       // f32 [k][b][sp][d], written stage E
  float* o2     = ws + OFF_O2;

  // bf16 / scan overlays (lifetimes verified against the stage timeline):
  short* featB = (short*)(ws + OFF_POOLED);            // written end A (pooled dead), read B
  short* wInB  = (short*)(ws + OFF_DELTA);             // read B; delta_sp written E (after B)
  short* wXB   = (short*)(ws + OFF_DELTA + 2097152);   // read D; delta_sp written E (after D)
  short* wOB   = (short*)(ws + OFF_FEAT);              // read H
  short* wCB   = (short*)(ws + OFF_PCONV);             // written after feat (pconv dead), read I
  short* xcB   = (short*)(ws + OFF_O1);                // written C, read D..pass2; o1B written H (after)
  short* oyB   = (short*)(ws + OFF_OUTY);              // written pass2 (16MB), read G
  float* Pa    = ws + OFF_OUTY + 4194304;              // written pass1 (8MB), read combine
  float* Hend  = ws + OFF_OUTY + 4194304 + 2097152;    // written pass1 (8MB), read combine
  short* dtwB  = (short*)(ws + OFF_OUTY + 4194304);    // read E; Pa written pass1 (after E)
  short* PB    = (short*)(ws + OFF_OUTY + 4194304 + 262144); // written after D, read E; inside Pa region
  float* Hstart= ws + OFF_YG;                          // written combine (8MB), read pass2
  short* ygB   = (short*)(ws + OFF_DELTA);             // written G (delta_sp dead after pass2), read H
  short* o1B   = (short*)(ws + OFF_O1);                // written H, read I
  // stage A: pyramid pooling
  pool0_kernel<<<Bsz*DIM, 256, 0, stream>>>(x, pool_w, pool_b, bn_g, bn_b, bn_m, bn_v, y0m);
  pool_avg_kernel<<<Bsz*Cin, 288, 0, stream>>>(x, pooled);
  pconv_kernel<<<Bsz*275, 128, 0, stream>>>(pooled, pool_w, pool_b, bn_g, bn_b, bn_m, bn_v, pconv);
  feat_kernel<<<Bsz*Lsp, 256, 0, stream>>>(x, y0m, pconv, featB);

  // weight conversions (after stage A so overlaid regions are dead)
  f2bf_kernel<<<(4096*1024)/2048, 256, 0, stream>>>(in_proj_w, wInB, 4096*1024);
  f2bf_kernel<<<(PW*2048)/2048,   256, 0, stream>>>(x_proj_w,  wXB,  PW*2048);
  f2bf_kernel<<<(1024*2048)/2048, 256, 0, stream>>>(out_proj_w, wOB, 1024*2048);
  f2bf_kernel<<<(DIM*1024)/2048,  256, 0, stream>>>(cbr_w,      wCB, DIM*1024);
  f2bf_kernel<<<(KK*DI*RR)/2048,  256, 0, stream>>>(dt_w,       dtwB, KK*DI*RR);

  // stage B: in_proj GEMM (M=1024, N=4096, K=1024), f32 out
  gemm_bf<0><<<dim3(4096/128, 1024/128), 256, 0, stream>>>(featB, wInB, xz, nullptr, 1024, 4096, 1024, 1024, 1024);

  // stage C: depthwise conv + silu -> bf16
  dwconv_kernel<<<Bsz*Lsp, 256, 0, stream>>>(xz, conv_w, conv_b, xcB);

  // stage D: x_proj GEMM: P[1024x384] = xcB * wXB^T (K=2048), f32 out
  gemm_bf<0><<<dim3(PW/128, 1024/128), 256, 0, stream>>>(xcB, wXB, P, nullptr, 1024, PW, 2048, 2048, 2048);

  // P -> bf16 for the delta GEMMs
  f2bf_kernel<<<(Bsz*Lsp*PW)/2048, 256, 0, stream>>>(P, PB, Bsz*Lsp*PW);

  // stage E: delta as 4 GEMMs (M=1024, N=2048, K=64) with softplus+bias epilogue,
  // output in spatial order delta_sp[k][b][sp][d]
  for (int k = 0; k < KK; ++k)
    gemm_bf<2><<<dim3(DI/128, 1024/128), 256, 0, stream>>>(PB + k*96, dtwB + (size_t)k*DI*RR,
        delta_sp + (size_t)k*Bsz*Lsp*DI, dt_b + k*DI, 1024, DI, 64, PW, RR);

  // stage F: chunked two-pass selective scan
  scan_pass1<<<dim3(Bsz*KK, DI/64, NCH), 256, 0, stream>>>(delta_sp, xcB, P, A_logs, Pa, Hend);
  scan_combine<<<(16*DI*NST)/256, 256, 0, stream>>>(Pa, Hend, Hstart);
  scan_pass2<<<dim3(Bsz*KK, DI/64, NCH), 256, 0, stream>>>(delta_sp, xcB, P, A_logs, Ds, Hstart, oyB);

  // stage G: combine + LN + gate -> bf16
  combine_ln_kernel<<<Bsz*Lsp, 256, 0, stream>>>(oyB, xz, ln_g, ln_b, ygB);

  // stage H: out_proj GEMM (M=1024, N=1024, K=2048), bf16 out
  gemm_bf<1><<<dim3(1024/128, 1024/128), 256, 0, stream>>>(ygB, wOB, o1B, nullptr, 1024, 1024, 2048, 2048, 2048);

  // stage I: cbr GEMM (M=1024, N=128, K=1024), f32 out + epilogue
  gemm_bf<0><<<dim3(DIM/128, 1024/128), 256, 0, stream>>>(o1B, wCB, o2, nullptr, 1024, DIM, 1024, 1024, 1024);
  cbr_epilogue<<<(Bsz*DIM*Lsp)/256, 256, 0, stream>>>(o2, cbr_b, cbr_g, cbr_beta, cbr_m, cbr_v, out);
}

// Round 7
// 417.214 us; speedup vs baseline: 1.0595x; 1.0595x over previous
//
#include <hip/hip_runtime.h>
#include <hip/hip_bf16.h>
#include <math.h>

// ---------- constants ----------
#define Bsz 4
#define Cin 512
#define Hh 16
#define Ww 16
#define Lsp 256
#define DIM 128
#define DM 1024      // dim*4 + 512
#define DI 2048
#define KK 4
#define NST 16
#define RR 64
#define PW 384       // K*96 projection rows
#define NCH 4
#define CHUNK 64     // Lsp / NCH

// ---------- ws layout (floats) — round-4 proven layout ----------
#define OFF_FEAT    0u
#define SZ_FEAT     (Bsz*Lsp*DM)                 // 1048576
#define OFF_POOLED  (OFF_FEAT + SZ_FEAT)
#define SZ_POOLED   (Bsz*Cin*275)                // 563200
#define OFF_PCONV   (OFF_POOLED + SZ_POOLED)
#define SZ_PCONV    (Bsz*275*DIM)                // 140800
#define OFF_Y0M     (OFF_PCONV + SZ_PCONV)
#define SZ_Y0M      (Bsz*DIM)                    // 512
#define OFF_XZ      (OFF_Y0M + SZ_Y0M)
#define SZ_XZ       (Bsz*Lsp*2*DI)               // 4194304
#define OFF_XCT     (OFF_XZ + SZ_XZ)
#define SZ_XCT      (Bsz*Lsp*DI)                 // 2097152 (unused)
#define OFF_XDBL    (OFF_XCT + SZ_XCT)
#define SZ_XDBL     (Bsz*Lsp*PW)                 // 393216  (P matrix f32)
#define OFF_DELTA   (OFF_XDBL + SZ_XDBL)
#define SZ_DELTA    (Bsz*KK*Lsp*DI)              // 8388608 (delta_sp f32)
#define OFF_OUTY    (OFF_DELTA + SZ_DELTA)
#define SZ_OUTY     (Bsz*KK*Lsp*DI)              // 8388608 (oyB bf16 + Pa + Hend)
#define OFF_YG      (OFF_OUTY + SZ_OUTY)
#define SZ_YG       (Bsz*Lsp*DI)                 // 2097152 (Hstart)
#define OFF_O1      (OFF_YG + SZ_YG)
#define SZ_O1       (Bsz*Lsp*DM)                 // 1048576 (xcB then o1B)
#define OFF_O2      (OFF_O1 + SZ_O1)
#define SZ_O2       (Bsz*Lsp*DIM)                // 131072
#define WS_FLOATS   (OFF_O2 + SZ_O2)

typedef __attribute__((ext_vector_type(8))) short short8;
typedef __attribute__((ext_vector_type(4))) float f32x4;

__device__ __forceinline__ short f2bf(float x) {
  __hip_bfloat16 h = __float2bfloat16(x);
  short s;
  __builtin_memcpy(&s, &h, 2);
  return s;
}
__device__ __forceinline__ float bf2f(short s) {
  unsigned u = ((unsigned)(unsigned short)s) << 16;
  float f;
  __builtin_memcpy(&f, &u, 4);
  return f;
}

// ---------- f32 -> bf16 bulk convert (n multiple of 8) ----------
__global__ __launch_bounds__(256) void f2bf_kernel(const float* __restrict__ in,
    short* __restrict__ out, int n) {
  int i = (blockIdx.x*256 + threadIdx.x)*8;
  if (i >= n) return;
  float4 a = *(const float4*)(in + i);
  float4 b = *(const float4*)(in + i + 4);
  short8 o;
  o[0]=f2bf(a.x); o[1]=f2bf(a.y); o[2]=f2bf(a.z); o[3]=f2bf(a.w);
  o[4]=f2bf(b.x); o[5]=f2bf(b.y); o[6]=f2bf(b.z); o[7]=f2bf(b.w);
  *(short8*)(out + i) = o;
}

// ---------- pool layer 0: conv1x1+BN+ReLU then global mean (ILP version) ----------
__global__ __launch_bounds__(256) void pool0_kernel(
    const float* __restrict__ x, const float* __restrict__ pw, const float* __restrict__ pb,
    const float* __restrict__ g, const float* __restrict__ bb,
    const float* __restrict__ m, const float* __restrict__ v, float* __restrict__ y0m) {
  int bd = blockIdx.x;             // b*128+d
  int b = bd >> 7, d = bd & 127;
  int l = threadIdx.x;
  const float* xb = x + (b*Cin)*Lsp + l;
  const float* w = pw + d*Cin;     // layer 0, 16B-aligned (d*512 floats)
  float a0 = 0.f, a1 = 0.f, a2 = 0.f, a3 = 0.f;
  #pragma unroll 4
  for (int c = 0; c < Cin; c += 4) {
    float4 wv = *(const float4*)(w + c);
    a0 += xb[(c+0)*Lsp] * wv.x;
    a1 += xb[(c+1)*Lsp] * wv.y;
    a2 += xb[(c+2)*Lsp] * wv.z;
    a3 += xb[(c+3)*Lsp] * wv.w;
  }
  float s = (a0 + a1) + (a2 + a3) + pb[d];
  float inv = g[d] * rsqrtf(v[d] + 1e-5f);
  s = s*inv + (bb[d] - m[d]*inv);
  s = fmaxf(s, 0.f);
  __shared__ float red[256];
  red[l] = s; __syncthreads();
  for (int off = 128; off > 0; off >>= 1) {
    if (l < off) red[l] += red[l+off];
    __syncthreads();
  }
  if (l == 0) y0m[bd] = red[0] * (1.f/256.f);
}

// ---------- adaptive avg pool of x to 5x5,9x9,13x13 (concatenated 275 positions) ----------
__device__ __forceinline__ void decode_pos(int pos, int& s, int& pp, int& qq, int& layer) {
  if (pos < 25)       { s = 5;  layer = 1; int t = pos;       pp = t/5;  qq = t%5;  }
  else if (pos < 106) { s = 9;  layer = 2; int t = pos - 25;  pp = t/9;  qq = t%9;  }
  else                { s = 13; layer = 3; int t = pos - 106; pp = t/13; qq = t%13; }
}

__global__ void pool_avg_kernel(const float* __restrict__ x, float* __restrict__ pooled) {
  int bc = blockIdx.x;             // b*512+c
  int pos = threadIdx.x;
  if (pos >= 275) return;
  int s, pp, qq, layer;
  decode_pos(pos, s, pp, qq, layer);
  int hs = (pp*Hh)/s, he = ((pp+1)*Hh + s-1)/s;
  int ws = (qq*Ww)/s, we = ((qq+1)*Ww + s-1)/s;
  const float* xb = x + (size_t)bc*Lsp;
  float acc = 0.f;
  for (int hh = hs; hh < he; ++hh)
    for (int ww2 = ws; ww2 < we; ++ww2)
      acc += xb[hh*Ww + ww2];
  pooled[(size_t)bc*275 + pos] = acc / (float)((he-hs)*(we-ws));
}

// ---------- conv1x1 + BN + ReLU on pooled features (ILP version) ----------
__global__ void pconv_kernel(const float* __restrict__ pooled, const float* __restrict__ pw,
    const float* __restrict__ pb, const float* __restrict__ g, const float* __restrict__ bb,
    const float* __restrict__ m, const float* __restrict__ v, float* __restrict__ pconv) {
  int bp = blockIdx.x;             // b*275+pos
  int b = bp / 275, pos = bp % 275;
  int d = threadIdx.x;             // 0..127
  int s, pp, qq, layer;
  decode_pos(pos, s, pp, qq, layer);
  const float* pc = pooled + b*Cin*275 + pos;
  const float* w = pw + (layer*DIM + d)*Cin;   // 16B-aligned
  float a0 = 0.f, a1 = 0.f, a2 = 0.f, a3 = 0.f;
  #pragma unroll 4
  for (int c = 0; c < Cin; c += 4) {
    float4 wv = *(const float4*)(w + c);
    a0 += pc[(c+0)*275] * wv.x;
    a1 += pc[(c+1)*275] * wv.y;
    a2 += pc[(c+2)*275] * wv.z;
    a3 += pc[(c+3)*275] * wv.w;
  }
  float acc = (a0 + a1) + (a2 + a3) + pb[layer*DIM + d];
  int ld = layer*DIM + d;
  float inv = g[ld] * rsqrtf(v[ld] + 1e-5f);
  acc = acc*inv + (bb[ld] - m[ld]*inv);
  pconv[bp*DIM + d] = fmaxf(acc, 0.f);
}

// ---------- assemble feat (B,L,1024) in bf16 ----------
__global__ __launch_bounds__(256) void feat_kernel(const float* __restrict__ x,
    const float* __restrict__ y0m, const float* __restrict__ pconv, short* __restrict__ featB) {
  int bl = blockIdx.x;             // b*256+l
  int b = bl >> 8, l = bl & 255;
  int h = l >> 4, w = l & 15;
  for (int c = threadIdx.x; c < DM; c += 256) {
    float val;
    if (c < Cin) {
      val = x[(b*Cin + c)*Lsp + l];
    } else if (c < Cin + DIM) {
      val = y0m[b*DIM + (c - Cin)];
    } else {
      int i = (c - (Cin+DIM)) >> 7;          // 0,1,2 -> s=5,9,13
      int d = (c - (Cin+DIM)) & 127;
      int s = (i==0) ? 5 : (i==1) ? 9 : 13;
      int off = (i==0) ? 0 : (i==1) ? 25 : 106;
      float scale = (float)s / 16.f;
      float sh = fmaxf((h + 0.5f)*scale - 0.5f, 0.f);
      int h0 = min((int)sh, s-1); float wh = sh - (float)h0; int h1 = min(h0+1, s-1);
      float sw = fmaxf((w + 0.5f)*scale - 0.5f, 0.f);
      int w0 = min((int)sw, s-1); float ww2 = sw - (float)w0; int w1 = min(w0+1, s-1);
      const float* pc = pconv + b*275*DIM;
      float v00 = pc[(off + h0*s + w0)*DIM + d];
      float v01 = pc[(off + h0*s + w1)*DIM + d];
      float v10 = pc[(off + h1*s + w0)*DIM + d];
      float v11 = pc[(off + h1*s + w1)*DIM + d];
      val = (1.f-wh)*((1.f-ww2)*v00 + ww2*v01) + wh*((1.f-ww2)*v10 + ww2*v11);
    }
    featB[bl*DM + c] = f2bf(val);
  }
}

// ---------- bf16 MFMA GEMM: C[M][N] = A[M][K] * B[N][K]^T ----------
// MODE 0: f32 store.  MODE 1: bf16 store.  MODE 2: f32 softplus(acc + bias[col]).
__device__ __forceinline__ void gload_lds16(const short* g, short* l) {
  __builtin_amdgcn_global_load_lds((const __attribute__((address_space(1))) void*)g,
                                   (__attribute__((address_space(3))) void*)l, 16, 0, 0);
}

template<int MODE>
__global__ __launch_bounds__(256) void gemm_bf(const short* __restrict__ Ag,
    const short* __restrict__ Bg, void* __restrict__ Cout, const float* __restrict__ bias,
    int M, int N, int K, int lda, int ldb) {
  __shared__ short Als[128*64];
  __shared__ short Bls[128*64];
  int tid = threadIdx.x;
  int w = tid >> 6, lane = tid & 63;
  int wm = w >> 1, wn = w & 1;
  int row0 = blockIdx.y * 128, col0 = blockIdx.x * 128;
  f32x4 acc[4][4];
  #pragma unroll
  for (int i = 0; i < 4; ++i)
    #pragma unroll
    for (int j = 0; j < 4; ++j)
      acc[i][j] = (f32x4){0.f, 0.f, 0.f, 0.f};

  for (int k0 = 0; k0 < K; k0 += 64) {
    #pragma unroll
    for (int i = 0; i < 4; ++i) {
      int slot = i*256 + w*64 + lane;
      int r = slot >> 3, pc = slot & 7;
      int c = pc ^ (r & 7);                       // logical 16B-chunk for this slot
      gload_lds16(Ag + (size_t)(row0 + r)*lda + k0 + c*8, &Als[(i*256 + w*64)*8]);
      gload_lds16(Bg + (size_t)(col0 + r)*ldb + k0 + c*8, &Bls[(i*256 + w*64)*8]);
    }
    __syncthreads();
    #pragma unroll
    for (int ks = 0; ks < 2; ++ks) {
      short8 af[4], bfr[4];
      int rsel = lane & 15, csel = ks*4 + (lane >> 4);
      #pragma unroll
      for (int mi = 0; mi < 4; ++mi) {
        int row = wm*64 + mi*16 + rsel;
        af[mi] = *(const short8*)&Als[row*64 + ((csel ^ (row & 7)) << 3)];
      }
      #pragma unroll
      for (int ni = 0; ni < 4; ++ni) {
        int row = wn*64 + ni*16 + rsel;
        bfr[ni] = *(const short8*)&Bls[row*64 + ((csel ^ (row & 7)) << 3)];
      }
      #pragma unroll
      for (int mi = 0; mi < 4; ++mi)
        #pragma unroll
        for (int ni = 0; ni < 4; ++ni)
          acc[mi][ni] = __builtin_amdgcn_mfma_f32_16x16x32_bf16(af[mi], bfr[ni], acc[mi][ni], 0, 0, 0);
    }
    __syncthreads();
  }
  // epilogue: D row = (lane>>4)*4 + j, col = lane&15
  #pragma unroll
  for (int mi = 0; mi < 4; ++mi) {
    int rbase = row0 + wm*64 + mi*16 + ((lane >> 4) << 2);
    #pragma unroll
    for (int ni = 0; ni < 4; ++ni) {
      int colg = col0 + wn*64 + ni*16 + (lane & 15);
      #pragma unroll
      for (int j = 0; j < 4; ++j) {
        if (MODE == 1) {
          ((short*)Cout)[(size_t)(rbase + j)*N + colg] = f2bf(acc[mi][ni][j]);
        } else if (MODE == 2) {
          float sv = acc[mi][ni][j] + bias[colg];
          ((float*)Cout)[(size_t)(rbase + j)*N + colg] = (sv > 20.f) ? sv : log1pf(__expf(sv));
        } else {
          ((float*)Cout)[(size_t)(rbase + j)*N + colg] = acc[mi][ni][j];
        }
      }
    }
  }
}

// ---------- depthwise 3x3 conv + bias + silu -> xcB (bf16) ----------
__global__ __launch_bounds__(256) void dwconv_kernel(const float* __restrict__ xz,
    const float* __restrict__ cw, const float* __restrict__ cb, short* __restrict__ xcB) {
  int bl = blockIdx.x;
  int b = bl >> 8, l = bl & 255;
  int h = l >> 4, w = l & 15;
  const float* xzb = xz + (size_t)b*Lsp*(2*DI);
  for (int d = threadIdx.x; d < DI; d += 256) {
    float s = 0.f;
    #pragma unroll
    for (int dh = -1; dh <= 1; ++dh) {
      int hh = h + dh; if (hh < 0 || hh > 15) continue;
      #pragma unroll
      for (int dw = -1; dw <= 1; ++dw) {
        int ww2 = w + dw; if (ww2 < 0 || ww2 > 15) continue;
        s += xzb[(size_t)(hh*16 + ww2)*(2*DI) + d] * cw[d*9 + (dh+1)*3 + (dw+1)];
      }
    }
    s += cb[d];
    float r = s / (1.f + __expf(-s));   // silu
    xcB[((size_t)b*Lsp + l)*DI + d] = f2bf(r);
  }
}

// scan-direction spatial index map
__device__ __forceinline__ int dir_map(int k, int l) {
  if (k == 0) return l;
  if (k == 1) return ((l & 15) << 4) | (l >> 4);
  if (k == 2) return 255 - l;
  int m = 255 - l; return ((m & 15) << 4) | (m >> 4);
}

// ---------- scan pass 1: per-chunk local scan -> Pa (decay product), Hend ----------
__global__ __launch_bounds__(256) void scan_pass1(const float* __restrict__ delta_sp,
    const short* __restrict__ xcB, const float* __restrict__ P,
    const float* __restrict__ A_logs, float* __restrict__ Pa, float* __restrict__ Hend) {
  int bk = blockIdx.x;             // b*4+k
  int b = bk >> 2, k = bk & 3;
  int tid = threadIdx.x;
  int wv = tid >> 6, lane = tid & 63;
  int dloc = lane >> 2, ng = lane & 3;
  int d = blockIdx.y*64 + wv*16 + dloc;
  int c = blockIdx.z;
  int n0 = ng*4;
  float A[4], h[4] = {0.f,0.f,0.f,0.f}, pa[4] = {1.f,1.f,1.f,1.f};
  #pragma unroll
  for (int j = 0; j < 4; ++j)
    A[j] = -__expf(A_logs[((size_t)k*DI + d)*NST + n0 + j]);
  const float* dsp = delta_sp + (size_t)(k*Bsz + b)*Lsp*DI;
  const short* xc  = xcB + (size_t)b*Lsp*DI;
  for (int l = c*CHUNK; l < (c+1)*CHUNK; ++l) {
    int sp = dir_map(k, l);
    const float* pr = P + (size_t)(b*Lsp + sp)*PW + k*96;
    float dl = dsp[(size_t)sp*DI + d];
    float ul = bf2f(xc[(size_t)sp*DI + d]);
    float du = dl * ul;
    float4 Bv = *(const float4*)(pr + RR + n0);
    float e0 = __expf(dl*A[0]); h[0] = h[0]*e0 + du*Bv.x; pa[0] *= e0;
    float e1 = __expf(dl*A[1]); h[1] = h[1]*e1 + du*Bv.y; pa[1] *= e1;
    float e2 = __expf(dl*A[2]); h[2] = h[2]*e2 + du*Bv.z; pa[2] *= e2;
    float e3 = __expf(dl*A[3]); h[3] = h[3]*e3 + du*Bv.w; pa[3] *= e3;
  }
  size_t base = ((size_t)(c*16 + bk)*DI + d)*NST + n0;
  #pragma unroll
  for (int j = 0; j < 4; ++j) {
    Pa[base + j] = pa[j];
    Hend[base + j] = h[j];
  }
}

// ---------- combine chunk boundaries ----------
__global__ __launch_bounds__(256) void scan_combine(const float* __restrict__ Pa,
    const float* __restrict__ Hend, float* __restrict__ Hstart) {
  int idx = blockIdx.x*256 + threadIdx.x;    // (bk*DI + d)*16 + n
  const int stride = 16*DI*NST;              // 524288
  float h = 0.f;
  #pragma unroll
  for (int c = 0; c < NCH; ++c) {
    Hstart[c*stride + idx] = h;
    h = Pa[c*stride + idx]*h + Hend[c*stride + idx];
  }
}

// ---------- scan pass 2: rescan with correct Hstart, emit y (bf16) ----------
__global__ __launch_bounds__(256) void scan_pass2(const float* __restrict__ delta_sp,
    const short* __restrict__ xcB, const float* __restrict__ P,
    const float* __restrict__ A_logs, const float* __restrict__ Ds,
    const float* __restrict__ Hstart, short* __restrict__ oyB) {
  int bk = blockIdx.x;             // b*4+k
  int b = bk >> 2, k = bk & 3;
  int tid = threadIdx.x;
  int wv = tid >> 6, lane = tid & 63;
  int dloc = lane >> 2, ng = lane & 3;
  int d = blockIdx.y*64 + wv*16 + dloc;
  int c = blockIdx.z;
  int n0 = ng*4;
  float A[4], h[4];
  #pragma unroll
  for (int j = 0; j < 4; ++j)
    A[j] = -__expf(A_logs[((size_t)k*DI + d)*NST + n0 + j]);
  size_t hbase = ((size_t)(c*16 + bk)*DI + d)*NST + n0;
  #pragma unroll
  for (int j = 0; j < 4; ++j) h[j] = Hstart[hbase + j];
  float Dv = Ds[k*DI + d];
  const float* dsp = delta_sp + (size_t)(k*Bsz + b)*Lsp*DI;
  const short* xc  = xcB + (size_t)b*Lsp*DI;
  short* oy = oyB + (size_t)bk*Lsp*DI;
  for (int l = c*CHUNK; l < (c+1)*CHUNK; ++l) {
    int sp = dir_map(k, l);
    const float* pr = P + (size_t)(b*Lsp + sp)*PW + k*96;
    float dl = dsp[(size_t)sp*DI + d];
    float ul = bf2f(xc[(size_t)sp*DI + d]);
    float du = dl * ul;
    float4 Bv = *(const float4*)(pr + RR + n0);
    float4 Cv = *(const float4*)(pr + RR + NST + n0);
    float y;
    float e0 = __expf(dl*A[0]); h[0] = h[0]*e0 + du*Bv.x; y  = h[0]*Cv.x;
    float e1 = __expf(dl*A[1]); h[1] = h[1]*e1 + du*Bv.y; y += h[1]*Cv.y;
    float e2 = __expf(dl*A[2]); h[2] = h[2]*e2 + du*Bv.z; y += h[2]*Cv.z;
    float e3 = __expf(dl*A[3]); h[3] = h[3]*e3 + du*Bv.w; y += h[3]*Cv.w;
    y += __shfl_xor(y, 1);
    y += __shfl_xor(y, 2);
    if (ng == 0) oy[(size_t)l*DI + d] = f2bf(y + Dv*ul);
  }
}

// ---------- combine 4 directions + LayerNorm + gate with silu(z) -> bf16 ----------
__global__ __launch_bounds__(256) void combine_ln_kernel(const short* __restrict__ oyB,
    const float* __restrict__ xz, const float* __restrict__ lng, const float* __restrict__ lnb,
    short* __restrict__ ygB) {
  int bl = blockIdx.x;
  int b = bl >> 8, l = bl & 255;
  int h = l >> 4, w = l & 15;
  int lT = (w << 4) | h;
  const short* oy = oyB + (size_t)b*KK*Lsp*DI;
  float vals[8];
  float sum = 0.f, sumsq = 0.f;
  #pragma unroll
  for (int i = 0; i < 8; ++i) {
    int d = threadIdx.x + i*256;
    float yv = bf2f(oy[(size_t)(0*Lsp + l       )*DI + d])
             + bf2f(oy[(size_t)(2*Lsp + (255-l ))*DI + d])
             + bf2f(oy[(size_t)(1*Lsp + lT      )*DI + d])
             + bf2f(oy[(size_t)(3*Lsp + (255-lT))*DI + d]);
    vals[i] = yv; sum += yv; sumsq += yv*yv;
  }
  __shared__ float r1[256], r2[256];
  r1[threadIdx.x] = sum; r2[threadIdx.x] = sumsq; __syncthreads();
  for (int off = 128; off > 0; off >>= 1) {
    if (threadIdx.x < off) { r1[threadIdx.x] += r1[threadIdx.x+off]; r2[threadIdx.x] += r2[threadIdx.x+off]; }
    __syncthreads();
  }
  float mu = r1[0] * (1.f/2048.f);
  float var = r2[0] * (1.f/2048.f) - mu*mu;
  float rstd = rsqrtf(var + 1e-5f);
  const float* zrow = xz + (size_t)bl*(2*DI) + DI;
  #pragma unroll
  for (int i = 0; i < 8; ++i) {
    int d = threadIdx.x + i*256;
    float z = zrow[d];
    float sz = z / (1.f + __expf(-z));
    ygB[(size_t)bl*DI + d] = f2bf(((vals[i]-mu)*rstd*lng[d] + lnb[d]) * sz);
  }
}

// ---------- cbr epilogue: bias + BN + exact GELU, write NCHW ----------
__global__ void cbr_epilogue(const float* __restrict__ o2, const float* __restrict__ cb,
    const float* __restrict__ g, const float* __restrict__ beta, const float* __restrict__ m_,
    const float* __restrict__ v_, float* __restrict__ out) {
  int idx = blockIdx.x*256 + threadIdx.x;   // (b*128+dd)*256 + l
  int l = idx & 255;
  int rest = idx >> 8;
  int dd = rest & 127;
  int b = rest >> 7;
  float s = o2[((size_t)b*Lsp + l)*DIM + dd] + cb[dd];
  float inv = g[dd] * rsqrtf(v_[dd] + 1e-5f);
  s = s*inv + (beta[dd] - m_[dd]*inv);
  out[idx] = s * 0.5f * (1.f + erff(s * 0.70710678118f));
}

extern "C" void kernel_launch(void* const* d_in, const int* in_sizes, int n_in,
                              void* d_out, int out_size, void* d_ws, size_t ws_size,
                              hipStream_t stream) {
  const float* x        = (const float*)d_in[0];
  const float* pool_w   = (const float*)d_in[1];
  const float* pool_b   = (const float*)d_in[2];
  const float* bn_g     = (const float*)d_in[3];
  const float* bn_b     = (const float*)d_in[4];
  const float* bn_m     = (const float*)d_in[5];
  const float* bn_v     = (const float*)d_in[6];
  const float* in_proj_w= (const float*)d_in[7];
  const float* conv_w   = (const float*)d_in[8];
  const float* conv_b   = (const float*)d_in[9];
  const float* x_proj_w = (const float*)d_in[10];
  const float* dt_w     = (const float*)d_in[11];
  const float* dt_b     = (const float*)d_in[12];
  const float* A_logs   = (const float*)d_in[13];
  const float* Ds       = (const float*)d_in[14];
  const float* ln_g     = (const float*)d_in[15];
  const float* ln_b     = (const float*)d_in[16];
  const float* out_proj_w=(const float*)d_in[17];
  const float* cbr_w    = (const float*)d_in[18];
  const float* cbr_b    = (const float*)d_in[19];
  const float* cbr_g    = (const float*)d_in[20];
  const float* cbr_beta = (const float*)d_in[21];
  const float* cbr_m    = (const float*)d_in[22];
  const float* cbr_v    = (const float*)d_in[23];
  float* out = (float*)d_out;

  if (ws_size < (size_t)WS_FLOATS * sizeof(float)) return;
  float* ws = (float*)d_ws;
  float* pooled   = ws + OFF_POOLED;
  float* pconv    = ws + OFF_PCONV;
  float* y0m      = ws + OFF_Y0M;
  float* xz       = ws + OFF_XZ;
  float* P        = ws + OFF_XDBL;
  float* delta_sp = ws + OFF_DELTA;
  float* o2       = ws + OFF_O2;

  // bf16 / scan overlays (round-4 proven lifetimes):
  short* featB = (short*)(ws + OFF_POOLED);            // written end A (pooled dead), read B
  short* wInB  = (short*)(ws + OFF_DELTA);             // read B; delta_sp written E
  short* wXB   = (short*)(ws + OFF_DELTA + 2097152);   // read D; delta_sp written E
  short* wOB   = (short*)(ws + OFF_FEAT);              // read H
  short* wCB   = (short*)(ws + OFF_PCONV);             // written after feat (pconv dead), read I
  short* xcB   = (short*)(ws + OFF_O1);                // written C, read D..pass2; o1B after
  short* oyB   = (short*)(ws + OFF_OUTY);              // written pass2, read G
  float* Pa    = ws + OFF_OUTY + 4194304;              // written pass1, read combine
  float* Hend  = ws + OFF_OUTY + 4194304 + 2097152;    // written pass1, read combine
  short* dtwB  = (short*)(ws + OFF_OUTY + 4194304);    // read E; Pa written pass1 (after E)
  short* PB    = (short*)(ws + OFF_OUTY + 4194304 + 262144); // written after D, read E
  float* Hstart= ws + OFF_YG;                          // written combine, read pass2
  short* ygB   = (short*)(ws + OFF_DELTA);             // written G (delta_sp dead), read H
  short* o1B   = (short*)(ws + OFF_O1);                // written H, read I

  // stage A: pyramid pooling
  pool0_kernel<<<Bsz*DIM, 256, 0, stream>>>(x, pool_w, pool_b, bn_g, bn_b, bn_m, bn_v, y0m);
  pool_avg_kernel<<<Bsz*Cin, 288, 0, stream>>>(x, pooled);
  pconv_kernel<<<Bsz*275, 128, 0, stream>>>(pooled, pool_w, pool_b, bn_g, bn_b, bn_m, bn_v, pconv);
  feat_kernel<<<Bsz*Lsp, 256, 0, stream>>>(x, y0m, pconv, featB);

  // weight conversions (after stage A so overlaid regions are dead)
  f2bf_kernel<<<(4096*1024)/2048, 256, 0, stream>>>(in_proj_w, wInB, 4096*1024);
  f2bf_kernel<<<(PW*2048)/2048,   256, 0, stream>>>(x_proj_w,  wXB,  PW*2048);
  f2bf_kernel<<<(1024*2048)/2048, 256, 0, stream>>>(out_proj_w, wOB, 1024*2048);
  f2bf_kernel<<<(DIM*1024)/2048,  256, 0, stream>>>(cbr_w,      wCB, DIM*1024);
  f2bf_kernel<<<(KK*DI*RR)/2048,  256, 0, stream>>>(dt_w,       dtwB, KK*DI*RR);

  // stage B: in_proj GEMM (M=1024, N=4096, K=1024), f32 out
  gemm_bf<0><<<dim3(4096/128, 1024/128), 256, 0, stream>>>(featB, wInB, xz, nullptr, 1024, 4096, 1024, 1024, 1024);

  // stage C: depthwise conv + silu -> bf16
  dwconv_kernel<<<Bsz*Lsp, 256, 0, stream>>>(xz, conv_w, conv_b, xcB);

  // stage D: x_proj GEMM: P[1024x384] = xcB * wXB^T (K=2048), f32 out
  gemm_bf<0><<<dim3(PW/128, 1024/128), 256, 0, stream>>>(xcB, wXB, P, nullptr, 1024, PW, 2048, 2048, 2048);
  f2bf_kernel<<<(Bsz*Lsp*PW)/2048, 256, 0, stream>>>(P, PB, Bsz*Lsp*PW);

  // stage E: delta as 4 GEMMs (M=1024, N=2048, K=64) with softplus+bias epilogue,
  // output in spatial order delta_sp[k][b][sp][d]
  for (int k = 0; k < KK; ++k)
    gemm_bf<2><<<dim3(DI/128, 1024/128), 256, 0, stream>>>(PB + k*96, dtwB + (size_t)k*DI*RR,
        delta_sp + (size_t)k*Bsz*Lsp*DI, dt_b + k*DI, 1024, DI, 64, PW, RR);

  // stage F: chunked two-pass selective scan
  scan_pass1<<<dim3(Bsz*KK, DI/64, NCH), 256, 0, stream>>>(delta_sp, xcB, P, A_logs, Pa, Hend);
  scan_combine<<<(16*DI*NST)/256, 256, 0, stream>>>(Pa, Hend, Hstart);
  scan_pass2<<<dim3(Bsz*KK, DI/64, NCH), 256, 0, stream>>>(delta_sp, xcB, P, A_logs, Ds, Hstart, oyB);

  // stage G: combine + LN + gate -> bf16 (delta_sp dead; ygB overlays it)
  combine_ln_kernel<<<Bsz*Lsp, 256, 0, stream>>>(oyB, xz, ln_g, ln_b, ygB);

  // stage H: out_proj GEMM (M=1024, N=1024, K=2048), bf16 out
  gemm_bf<1><<<dim3(1024/128, 1024/128), 256, 0, stream>>>(ygB, wOB, o1B, nullptr, 1024, 1024, 2048, 2048, 2048);

  // stage I: cbr GEMM (M=1024, N=128, K=1024), f32 out + epilogue
  gemm_bf<0><<<dim3(DIM/128, 1024/128), 256, 0, stream>>>(o1B, wCB, o2, nullptr, 1024, DIM, 1024, 1024, 1024);
  cbr_epilogue<<<(Bsz*DIM*Lsp)/256, 256, 0, stream>>>(o2, cbr_b, cbr_g, cbr_beta, cbr_m, cbr_v, out);
}